// Round 10
// baseline (76.145 us; speedup 1.0000x reference)
//
#include <hip/hip_runtime.h>

#define NHEADS 16
#define HDIM   64
#define NFEAT  32
#define PDIM   16
#define NQUAD  2
#define GB     8
#define WAVES_PB 4

typedef float f32x4 __attribute__((ext_vector_type(4)));

// ============================================================================
// Kernel A: features only. prf_ws[b][r][h][m] (16MB), poly_ws[b][h][p] (4MB).
// Same compute core as the 62.4us kernel; stores are 20MB instead of 256MB.
// ============================================================================
__global__ __launch_bounds__(256, 3)
void slay_features(const float* __restrict__ x,
                   const float* __restrict__ omega,
                   const float* __restrict__ anchors,
                   const float* __restrict__ qn,
                   const float* __restrict__ qw,
                   float* __restrict__ prf_ws,
                   float* __restrict__ poly_ws)
{
    __shared__ __align__(16) float s_xn[WAVES_PB][64];

    const int tid  = threadIdx.x;
    const int wv   = tid >> 6;
    const int lane = tid & 63;
    const int h    = blockIdx.x & 15;
    const int b0   = ((blockIdx.x >> 4) * WAVES_PB + wv) * GB;

    const int r = lane >> 5;
    const int m = lane & 31;
    const int p = lane & 15;
    const int g = lane >> 4;

    const float sR     = fmaxf(qn[r], 1e-6f);
    const float sq2s   = sqrtf(2.0f * sR);
    const float scaleR = sqrtf(fmaxf(qw[r], 1e-6f)) / sqrtf(32.0f + 1e-6f);

    float om[64];
    {
        const float* oc = omega + ((size_t)(r * NHEADS + h) * HDIM) * NFEAT + m;
        #pragma unroll
        for (int d = 0; d < 64; ++d) om[d] = oc[(size_t)d * NFEAT];
    }
    float an[16];
    {
        const float* ac = anchors + p * HDIM + g * 16;
        #pragma unroll
        for (int dd = 0; dd < 16; ++dd) an[dd] = ac[dd];
    }

    float xvv[GB];
    {
        const float* xb = x + (size_t)b0 * (NHEADS * HDIM) + h * HDIM + lane;
        #pragma unroll
        for (int bb = 0; bb < GB; ++bb) xvv[bb] = xb[(size_t)bb * (NHEADS * HDIM)];
    }

    #pragma unroll
    for (int bb = 0; bb < GB; ++bb) {
        const int b = b0 + bb;

        float ss = xvv[bb] * xvv[bb];
        #pragma unroll
        for (int off = 32; off > 0; off >>= 1) ss += __shfl_xor(ss, off, 64);
        const float xn = xvv[bb] / fmaxf(sqrtf(ss), 1e-4f);

        __builtin_amdgcn_wave_barrier();
        s_xn[wv][lane] = xn;
        __builtin_amdgcn_wave_barrier();

        float a0 = 0.f, a1 = 0.f, a2 = 0.f, a3 = 0.f;
        #pragma unroll
        for (int d = 0; d < 64; d += 4) {
            const float s0 = __uint_as_float(__builtin_amdgcn_readlane(__float_as_uint(xn), d + 0));
            const float s1 = __uint_as_float(__builtin_amdgcn_readlane(__float_as_uint(xn), d + 1));
            const float s2 = __uint_as_float(__builtin_amdgcn_readlane(__float_as_uint(xn), d + 2));
            const float s3 = __uint_as_float(__builtin_amdgcn_readlane(__float_as_uint(xn), d + 3));
            a0 = fmaf(s0, om[d + 0], a0);
            a1 = fmaf(s1, om[d + 1], a1);
            a2 = fmaf(s2, om[d + 2], a2);
            a3 = fmaf(s3, om[d + 3], a3);
        }
        const float accR = (a0 + a1) + (a2 + a3);

        float p0 = 0.f, p1 = 0.f, p2 = 0.f, p3 = 0.f;
        #pragma unroll
        for (int q4 = 0; q4 < 4; ++q4) {
            const f32x4 xq = *(const f32x4*)&s_xn[wv][g * 16 + q4 * 4];
            p0 = fmaf(xq.x, an[q4 * 4 + 0], p0);
            p1 = fmaf(xq.y, an[q4 * 4 + 1], p1);
            p2 = fmaf(xq.z, an[q4 * 4 + 2], p2);
            p3 = fmaf(xq.w, an[q4 * 4 + 3], p3);
        }
        float accP = (p0 + p1) + (p2 + p3);
        accP += __shfl_xor(accP, 16, 64);
        accP += __shfl_xor(accP, 32, 64);

        const float arg  = fminf(fmaxf(accR * sq2s - sR, -20.f), 20.f);
        const float prf  = expf(arg) * scaleR;
        const float pc   = fminf(fmaxf(accP, -1.f), 1.f);
        const float poly = pc * pc * 0.25f;

        // prf_ws[b][r][h][m]: b*1024 + r*512 + h*32 + m  (two 128B chunks/wave)
        prf_ws[(size_t)b * 1024 + r * 512 + h * 32 + m] = prf;
        if (lane < 16)
            poly_ws[(size_t)b * 256 + h * 16 + p] = poly;
    }
}

// ============================================================================
// Kernel B: pure expansion stream. Fill-shaped: per thread-round, 2 cached
// loads + 4 muls + 1 f32x4 store. No LDS, no shfl, no barriers.
// out f32x4 j: b=j>>12, q=j&4095, r=q>>11, h=(q>>7)&15, p=(q>>3)&15, mg=q&7
// ============================================================================
__global__ __launch_bounds__(256)
void slay_expand(const float* __restrict__ prf_ws,
                 const float* __restrict__ poly_ws,
                 float* __restrict__ out)
{
    const f32x4* __restrict__ prf4 = (const f32x4*)prf_ws;
    f32x4* __restrict__ out4 = (f32x4*)out;

    const int j0 = blockIdx.x * 1024 + threadIdx.x;
    #pragma unroll
    for (int k = 0; k < 4; ++k) {
        const int j = j0 + k * 256;
        const int b  = j >> 12;
        const int q  = j & 4095;
        const int rr = q >> 11;
        const int hh = (q >> 7) & 15;
        const int pp = (q >> 3) & 15;
        const int mg = q & 7;
        const float pf = poly_ws[(b << 8) | (hh << 4) | pp];
        const f32x4 pr = prf4[(b << 8) | (rr << 7) | (hh << 3) | mg];
        f32x4 v;
        v.x = pf * pr.x; v.y = pf * pr.y; v.z = pf * pr.z; v.w = pf * pr.w;
        out4[j] = v;
    }
}

// ============================================================================
// Fallback (ws too small): the 62.4us single-kernel version.
// ============================================================================
__global__ __launch_bounds__(256, 3)
void slay_fused(const float* __restrict__ x,
                const float* __restrict__ omega,
                const float* __restrict__ anchors,
                const float* __restrict__ qn,
                const float* __restrict__ qw,
                float* __restrict__ out)
{
    __shared__ __align__(16) float s_xn [WAVES_PB][64];
    __shared__ __align__(16) float s_prf[WAVES_PB][64];
    __shared__ __align__(16) float s_poly[WAVES_PB][16];

    const int tid  = threadIdx.x;
    const int wv   = tid >> 6;
    const int lane = tid & 63;
    const int h    = blockIdx.x & 15;
    const int b0   = ((blockIdx.x >> 4) * WAVES_PB + wv) * GB;

    const int r = lane >> 5;
    const int m = lane & 31;
    const int p = lane & 15;
    const int g = lane >> 4;

    const float sR     = fmaxf(qn[r], 1e-6f);
    const float sq2s   = sqrtf(2.0f * sR);
    const float scaleR = sqrtf(fmaxf(qw[r], 1e-6f)) / sqrtf(32.0f + 1e-6f);

    float om[64];
    {
        const float* oc = omega + ((size_t)(r * NHEADS + h) * HDIM) * NFEAT + m;
        #pragma unroll
        for (int d = 0; d < 64; ++d) om[d] = oc[(size_t)d * NFEAT];
    }
    float an[16];
    {
        const float* ac = anchors + p * HDIM + g * 16;
        #pragma unroll
        for (int dd = 0; dd < 16; ++dd) an[dd] = ac[dd];
    }
    float xvv[GB];
    {
        const float* xb = x + (size_t)b0 * (NHEADS * HDIM) + h * HDIM + lane;
        #pragma unroll
        for (int bb = 0; bb < GB; ++bb) xvv[bb] = xb[(size_t)bb * (NHEADS * HDIM)];
    }

    #pragma unroll
    for (int bb = 0; bb < GB; ++bb) {
        const int b = b0 + bb;
        float ss = xvv[bb] * xvv[bb];
        #pragma unroll
        for (int off = 32; off > 0; off >>= 1) ss += __shfl_xor(ss, off, 64);
        const float xn = xvv[bb] / fmaxf(sqrtf(ss), 1e-4f);

        __builtin_amdgcn_wave_barrier();
        s_xn[wv][lane] = xn;
        __builtin_amdgcn_wave_barrier();

        float a0 = 0.f, a1 = 0.f, a2 = 0.f, a3 = 0.f;
        #pragma unroll
        for (int d = 0; d < 64; d += 4) {
            const float s0 = __uint_as_float(__builtin_amdgcn_readlane(__float_as_uint(xn), d + 0));
            const float s1 = __uint_as_float(__builtin_amdgcn_readlane(__float_as_uint(xn), d + 1));
            const float s2 = __uint_as_float(__builtin_amdgcn_readlane(__float_as_uint(xn), d + 2));
            const float s3 = __uint_as_float(__builtin_amdgcn_readlane(__float_as_uint(xn), d + 3));
            a0 = fmaf(s0, om[d + 0], a0);
            a1 = fmaf(s1, om[d + 1], a1);
            a2 = fmaf(s2, om[d + 2], a2);
            a3 = fmaf(s3, om[d + 3], a3);
        }
        const float accR = (a0 + a1) + (a2 + a3);

        float p0 = 0.f, p1 = 0.f, p2 = 0.f, p3 = 0.f;
        #pragma unroll
        for (int q4 = 0; q4 < 4; ++q4) {
            const f32x4 xq = *(const f32x4*)&s_xn[wv][g * 16 + q4 * 4];
            p0 = fmaf(xq.x, an[q4 * 4 + 0], p0);
            p1 = fmaf(xq.y, an[q4 * 4 + 1], p1);
            p2 = fmaf(xq.z, an[q4 * 4 + 2], p2);
            p3 = fmaf(xq.w, an[q4 * 4 + 3], p3);
        }
        float accP = (p0 + p1) + (p2 + p3);
        accP += __shfl_xor(accP, 16, 64);
        accP += __shfl_xor(accP, 32, 64);

        const float arg  = fminf(fmaxf(accR * sq2s - sR, -20.f), 20.f);
        const float prf  = expf(arg) * scaleR;
        const float pc   = fminf(fmaxf(accP, -1.f), 1.f);
        const float poly = pc * pc * 0.25f;

        __builtin_amdgcn_wave_barrier();
        s_prf[wv][lane] = prf;
        if (lane < 16) s_poly[wv][lane] = poly;
        __builtin_amdgcn_wave_barrier();

        float* ob = out + (size_t)b * (NQUAD * NHEADS * PDIM * NFEAT)
                        + (size_t)h * (PDIM * NFEAT);
        #pragma unroll
        for (int i4 = 0; i4 < 4; ++i4) {
            const int rr = i4 >> 1;
            const int pp = (i4 * 8 + (lane >> 3)) & 15;
            const float pf = s_poly[wv][pp];
            const f32x4 pr = *(const f32x4*)&s_prf[wv][rr * 32 + (lane & 7) * 4];
            f32x4 v;
            v.x = pf * pr.x; v.y = pf * pr.y; v.z = pf * pr.z; v.w = pf * pr.w;
            *(f32x4*)(ob + (size_t)rr * (NHEADS * PDIM * NFEAT)
                         + (i4 & 1) * 256 + lane * 4) = v;
        }
    }
}

extern "C" void kernel_launch(void* const* d_in, const int* in_sizes, int n_in,
                              void* d_out, int out_size, void* d_ws, size_t ws_size,
                              hipStream_t stream)
{
    const float* x       = (const float*)d_in[0];
    const float* omega   = (const float*)d_in[1];
    const float* anchors = (const float*)d_in[2];
    const float* qn      = (const float*)d_in[3];
    const float* qw      = (const float*)d_in[4];
    float* out = (float*)d_out;

    const int Bsz = in_sizes[0] / (NHEADS * HDIM);              // 4096
    const size_t prf_elems  = (size_t)Bsz * NQUAD * NHEADS * NFEAT;   // 4M
    const size_t poly_elems = (size_t)Bsz * NHEADS * PDIM;            // 1M
    const size_t need = (prf_elems + poly_elems) * sizeof(float);     // 20MB

    if (ws_size >= need) {
        float* prf_ws  = (float*)d_ws;
        float* poly_ws = prf_ws + prf_elems;
        dim3 gridA((Bsz / (WAVES_PB * GB)) * NHEADS);           // 2048
        slay_features<<<gridA, 256, 0, stream>>>(x, omega, anchors, qn, qw,
                                                 prf_ws, poly_ws);
        const int total_f32x4 = out_size / 4;                   // 16Mi
        dim3 gridB(total_f32x4 / 1024);                         // 16384
        slay_expand<<<gridB, 256, 0, stream>>>(prf_ws, poly_ws, out);
    } else {
        dim3 grid((Bsz / (WAVES_PB * GB)) * NHEADS);            // 2048
        slay_fused<<<grid, 256, 0, stream>>>(x, omega, anchors, qn, qw, out);
    }
}